// Round 14
// baseline (315.865 us; speedup 1.0000x reference)
//
#include <hip/hip_runtime.h>

#define NSTEPS 64

typedef __attribute__((ext_vector_type(16))) float float16_;   // 32x32 MFMA C/D
typedef __attribute__((ext_vector_type(2))) __fp16 half2_;     // packed f16
typedef __attribute__((ext_vector_type(8))) __fp16 half8_;     // f16 MFMA A/B operand

__device__ __forceinline__ half2_ relu_pk_f16(float a, float b) {
    half2_ h = __builtin_amdgcn_cvt_pkrtz(a, b);               // v_cvt_pkrtz_f16_f32
    return __builtin_elementwise_max(h, (half2_)(__fp16)0);    // v_pk_max_f16
}

// R13 layout (HW-verified this session; 32x32x16 f16 MFMA):
//   A[m][k]: m=lane&31, k=(lane>>5)*8+j      (two K-halves -> 2 chained MFMAs)
//   B[k][n]: n=lane&31, k=(lane>>5)*8+j      (same register mapping as A)
//   C/D[r][c]: c=lane&31, r=(reg&3)+8*(reg>>2)+4*(lane>>5)
// Transposed trick: D = mfma(W2^T, h1) -> lane holds h2^T rows
// j2 = (reg&3)+8*(reg>>2)+4*half for its own sample row c=lane&31; the row's
// other 16 j2 values live in lane^32 -> ONE shfl_xor(32) reduction round.
// R14: ONE group of 32 rows per wave -> 4096 waves = 4 waves/SIMD (TLP fills
// the dep-chain stalls that R13's 2-wave occupancy exposed); register demand
// halves so the arch-VGPR set fits the (256,4) 128-cap without AGPR stash.
__global__ __launch_bounds__(256, 4)
void ode_rk4_mfma(const float* __restrict__ x,
                  const float* __restrict__ samples,
                  const float* __restrict__ w1, const float* __restrict__ b1,
                  const float* __restrict__ w2, const float* __restrict__ b2,
                  const float* __restrict__ w3, const float* __restrict__ b3,
                  const float* __restrict__ w_out, const float* __restrict__ b_out,
                  float* __restrict__ out, int B)
{
    const int lane  = threadIdx.x & 63;
    const int w     = threadIdx.x >> 6;
    const int col32 = lane & 31;              // this lane's sample row (mod 32)
    const int half  = lane >> 5;              // 0..1

    const int rowBase = (blockIdx.x * 4 + w) * 32;
    const int row = rowBase + col32;          // lane's row (replicated over halves)

    // ---- persistent operands (built once; reused 1024 evals) ----
    // layer1 weights for fdot2, 16 h1-columns per lane:
    // i1 = half*8+jl (jl<8) or 16+half*8+(jl-8)
    half2_ w1p[16], w1q[16];
#pragma unroll
    for (int jl = 0; jl < 16; ++jl) {
        int i1 = (jl < 8) ? (half * 8 + jl) : (16 + half * 8 + (jl - 8));
        w1p[jl] = (half2_){(__fp16)w1[0 * 32 + i1], (__fp16)w1[1 * 32 + i1]};
        w1q[jl] = (half2_){(__fp16)w1[2 * 32 + i1], (__fp16)b1[i1]};
    }
    // W2^T A-frags: A[m=j2][k=i1] = w2[i1*32 + j2]; two K-halves
    union { half2_ h2[4]; half8_ h8; } W2T1, W2T2;
#pragma unroll
    for (int pp = 0; pp < 4; ++pp) {
        int i1 = half * 8 + 2 * pp;
        W2T1.h2[pp] = (half2_){(__fp16)w2[i1 * 32 + col32], (__fp16)w2[(i1 + 1) * 32 + col32]};
        W2T2.h2[pp] = (half2_){(__fp16)w2[(i1 + 16) * 32 + col32], (__fp16)w2[(i1 + 17) * 32 + col32]};
    }
    // bias C-frag: Cb[r] = b2[j2(r)] with j2 = (r&3)+8*(r>>2)+4*half
    float16_ Cb;
#pragma unroll
    for (int r = 0; r < 16; ++r)
        Cb[r] = b2[(r & 3) + 8 * (r >> 2) + 4 * half];
    // layer3 weights as f16 pairs matching D reg pairs: pair p -> j2_0 = 8*(p>>1)+2*(p&1)+4*half
    half2_ w3h[3][8];
#pragma unroll
    for (int d = 0; d < 3; ++d)
#pragma unroll
        for (int p = 0; p < 8; ++p) {
            int j0 = 8 * (p >> 1) + 2 * (p & 1) + 4 * half;
            w3h[d][p] = (half2_){(__fp16)w3[j0 * 3 + d], (__fp16)w3[(j0 + 1) * 3 + d]};
        }

    // ---- scalars ----
    const float maxT = samples[7];
    const float dt   = maxT / 64.0f;
    const float dt2  = 0.5f * dt;
    const float dt6  = dt / 6.0f;

    int sidx[8];
    unsigned long long smask = 0ull;
#pragma unroll
    for (int j = 0; j < 8; ++j) {
        int id = (int)rintf(samples[j] / dt) - 1;   // jnp.round = RNE
        id = id < 0 ? 0 : (id > NSTEPS - 1 ? NSTEPS - 1 : id);
        id = __builtin_amdgcn_readfirstlane(id);    // wave-uniform -> SGPR
        sidx[j] = id;
        smask |= 1ull << id;
    }
    const float wo0 = w_out[0], wo1 = w_out[1], wo2 = w_out[2];
    const float bo  = b_out[0];
    const float b30 = b3[0], b31 = b3[1], b32 = b3[2];

    float y0 = x[(size_t)row * 3 + 0];
    float y1 = x[(size_t)row * 3 + 1];
    float y2 = x[(size_t)row * 3 + 2];

#pragma unroll 1
    for (int s = 0; s < NSTEPS; ++s) {
        float acc0 = 0.f, acc1 = 0.f, acc2 = 0.f;
        float a0 = y0, a1 = y1, a2 = y2;

#pragma unroll
        for (int st = 0; st < 4; ++st) {
            // ---- layer1 via fdot2 (bias folded into dot) ----
            half2_ a01 = __builtin_amdgcn_cvt_pkrtz(a0, a1);
            half2_ a2o = __builtin_amdgcn_cvt_pkrtz(a2, 1.0f);
            float hf[16];
#pragma unroll
            for (int jl = 0; jl < 16; ++jl) {
                hf[jl] = __builtin_amdgcn_fdot2(a01, w1p[jl],
                         __builtin_amdgcn_fdot2(a2o, w1q[jl], 0.f, false), false);
            }
            // B operands: B#1 <- hf[0..7] (k=half*8+j), B#2 <- hf[8..15]
            union { half2_ h2[4]; half8_ h8; } B1, B2;
#pragma unroll
            for (int pp = 0; pp < 4; ++pp) {
                B1.h2[pp] = relu_pk_f16(hf[2 * pp], hf[2 * pp + 1]);
                B2.h2[pp] = relu_pk_f16(hf[8 + 2 * pp], hf[8 + 2 * pp + 1]);
            }

            // ---- layer2: two chained 32x32x16 MFMAs (K=32) ----
            float16_ D = __builtin_amdgcn_mfma_f32_32x32x16_f16(W2T1.h8, B1.h8,
                         __builtin_amdgcn_mfma_f32_32x32x16_f16(W2T2.h8, B2.h8, Cb, 0, 0, 0), 0, 0, 0);

            // ---- relu -> packed f16 pairs (reg pair p matches w3h pairing) ----
            half2_ h[8];
#pragma unroll
            for (int p = 0; p < 8; ++p)
                h[p] = relu_pk_f16(D[2 * p], D[2 * p + 1]);

            // ---- layer3 via fdot2 (24) ----
            float p0 = 0.f, p1 = 0.f, p2 = 0.f;
#pragma unroll
            for (int p = 0; p < 8; ++p) {
                p0 = __builtin_amdgcn_fdot2(h[p], w3h[0][p], p0, false);
                p1 = __builtin_amdgcn_fdot2(h[p], w3h[1][p], p1, false);
                p2 = __builtin_amdgcn_fdot2(h[p], w3h[2][p], p2, false);
            }

            // ---- ONE reduction round: lane^32 holds the row's other 16 j2 ----
            p0 += __shfl_xor(p0, 32);
            p1 += __shfl_xor(p1, 32);
            p2 += __shfl_xor(p2, 32);
            float k0 = p0 + b30, k1 = p1 + b31, k2 = p2 + b32;

            const float ca = (st == 1 || st == 2) ? 2.0f : 1.0f;
            acc0 = fmaf(ca, k0, acc0); acc1 = fmaf(ca, k1, acc1); acc2 = fmaf(ca, k2, acc2);
            const float ci = (st == 2) ? dt : dt2;
            a0 = fmaf(ci, k0, y0); a1 = fmaf(ci, k1, y1); a2 = fmaf(ci, k2, y2);
        }
        y0 = fmaf(dt6, acc0, y0); y1 = fmaf(dt6, acc1, y1); y2 = fmaf(dt6, acc2, y2);

        // wave-uniform SALU fast path: most steps store nothing
        if ((smask >> s) & 1ull) {
            if (half == 0) {
#pragma unroll
                for (int j = 0; j < 8; ++j) {
                    if (sidx[j] == s) {
                        out[(size_t)j * B + row] = fmaf(y2, wo2, fmaf(y1, wo1, fmaf(y0, wo0, bo)));
                    }
                }
            }
        }
    }
}

extern "C" void kernel_launch(void* const* d_in, const int* in_sizes, int n_in,
                              void* d_out, int out_size, void* d_ws, size_t ws_size,
                              hipStream_t stream) {
    const float* x       = (const float*)d_in[0];
    const float* samples = (const float*)d_in[1];
    const float* w1      = (const float*)d_in[2];
    const float* b1      = (const float*)d_in[3];
    const float* w2      = (const float*)d_in[4];
    const float* b2      = (const float*)d_in[5];
    const float* w3      = (const float*)d_in[6];
    const float* b3      = (const float*)d_in[7];
    const float* w_out   = (const float*)d_in[8];
    const float* b_out   = (const float*)d_in[9];
    float* out = (float*)d_out;

    const int B = in_sizes[0] / 3;           // 131072
    const int rowsPerBlock = 128;            // 4 waves x 32 rows (1 group each)
    const int grid = (B + rowsPerBlock - 1) / rowsPerBlock;
    ode_rk4_mfma<<<grid, 256, 0, stream>>>(
        x, samples, w1, b1, w2, b2, w3, b3, w_out, b_out, out, B);
}

// Round 15
// 303.083 us; speedup vs baseline: 1.0422x; 1.0422x over previous
//
#include <hip/hip_runtime.h>

#define NSTEPS 64

typedef __attribute__((ext_vector_type(16))) float float16_;   // 32x32 MFMA C/D
typedef __attribute__((ext_vector_type(2))) __fp16 half2_;     // packed f16
typedef __attribute__((ext_vector_type(8))) __fp16 half8_;     // f16 MFMA A/B operand

__device__ __forceinline__ half2_ relu_pk_f16(float a, float b) {
    half2_ h = __builtin_amdgcn_cvt_pkrtz(a, b);               // v_cvt_pkrtz_f16_f32
    return __builtin_elementwise_max(h, (half2_)(__fp16)0);    // v_pk_max_f16
}

// R13 layout (HW-verified this session; 32x32x16 f16 MFMA):
//   A[m][k]: m=lane&31, k=(lane>>5)*8+j      (two K-halves -> 2 chained MFMAs)
//   B[k][n]: n=lane&31, k=(lane>>5)*8+j      (same register mapping as A)
//   C/D[r][c]: c=lane&31, r=(reg&3)+8*(reg>>2)+4*(lane>>5)
// Transposed trick: D = mfma(W2^T, h1) -> lane holds h2^T rows for its own
// sample row; other 16 j2 live in lane^32 -> ONE shfl_xor(32) round.
// R15: gfx950 unified RF — __launch_bounds__ 2nd arg caps ARCH+ACC VGPRs
// combined at 512/waves. (256,4)=128 total -> stash+spill (R14: WRITE 14MB);
// (256,2)=256 -> ok but only 2 waves TLP (R13). (256,3)=170 total fits the
// ~120-reg demand with 3 waves/SIMD of latency hiding.
__global__ __launch_bounds__(256, 3)
void ode_rk4_mfma(const float* __restrict__ x,
                  const float* __restrict__ samples,
                  const float* __restrict__ w1, const float* __restrict__ b1,
                  const float* __restrict__ w2, const float* __restrict__ b2,
                  const float* __restrict__ w3, const float* __restrict__ b3,
                  const float* __restrict__ w_out, const float* __restrict__ b_out,
                  float* __restrict__ out, int B)
{
    const int lane  = threadIdx.x & 63;
    const int w     = threadIdx.x >> 6;
    const int col32 = lane & 31;              // this lane's sample row (mod 32)
    const int half  = lane >> 5;              // 0..1

    const int rowBase = (blockIdx.x * 4 + w) * 32;
    const int row = rowBase + col32;          // lane's row (replicated over halves)

    // ---- persistent operands (built once; reused 1024 evals) ----
    // layer1 weights for fdot2, 16 h1-columns per lane:
    // i1 = half*8+jl (jl<8) or 16+half*8+(jl-8)
    half2_ w1p[16], w1q[16];
#pragma unroll
    for (int jl = 0; jl < 16; ++jl) {
        int i1 = (jl < 8) ? (half * 8 + jl) : (16 + half * 8 + (jl - 8));
        w1p[jl] = (half2_){(__fp16)w1[0 * 32 + i1], (__fp16)w1[1 * 32 + i1]};
        w1q[jl] = (half2_){(__fp16)w1[2 * 32 + i1], (__fp16)b1[i1]};
    }
    // W2^T A-frags: A[m=j2][k=i1] = w2[i1*32 + j2]; two K-halves
    union { half2_ h2[4]; half8_ h8; } W2T1, W2T2;
#pragma unroll
    for (int pp = 0; pp < 4; ++pp) {
        int i1 = half * 8 + 2 * pp;
        W2T1.h2[pp] = (half2_){(__fp16)w2[i1 * 32 + col32], (__fp16)w2[(i1 + 1) * 32 + col32]};
        W2T2.h2[pp] = (half2_){(__fp16)w2[(i1 + 16) * 32 + col32], (__fp16)w2[(i1 + 17) * 32 + col32]};
    }
    // bias C-frag: Cb[r] = b2[j2(r)] with j2 = (r&3)+8*(r>>2)+4*half
    float16_ Cb;
#pragma unroll
    for (int r = 0; r < 16; ++r)
        Cb[r] = b2[(r & 3) + 8 * (r >> 2) + 4 * half];
    // layer3 weights as f16 pairs matching D reg pairs: pair p -> j2_0 = 8*(p>>1)+2*(p&1)+4*half
    half2_ w3h[3][8];
#pragma unroll
    for (int d = 0; d < 3; ++d)
#pragma unroll
        for (int p = 0; p < 8; ++p) {
            int j0 = 8 * (p >> 1) + 2 * (p & 1) + 4 * half;
            w3h[d][p] = (half2_){(__fp16)w3[j0 * 3 + d], (__fp16)w3[(j0 + 1) * 3 + d]};
        }

    // ---- scalars ----
    const float maxT = samples[7];
    const float dt   = maxT / 64.0f;
    const float dt2  = 0.5f * dt;
    const float dt6  = dt / 6.0f;

    int sidx[8];
    unsigned long long smask = 0ull;
#pragma unroll
    for (int j = 0; j < 8; ++j) {
        int id = (int)rintf(samples[j] / dt) - 1;   // jnp.round = RNE
        id = id < 0 ? 0 : (id > NSTEPS - 1 ? NSTEPS - 1 : id);
        id = __builtin_amdgcn_readfirstlane(id);    // wave-uniform -> SGPR
        sidx[j] = id;
        smask |= 1ull << id;
    }
    const float wo0 = w_out[0], wo1 = w_out[1], wo2 = w_out[2];
    const float bo  = b_out[0];
    const float b30 = b3[0], b31 = b3[1], b32 = b3[2];

    float y0 = x[(size_t)row * 3 + 0];
    float y1 = x[(size_t)row * 3 + 1];
    float y2 = x[(size_t)row * 3 + 2];

#pragma unroll 1
    for (int s = 0; s < NSTEPS; ++s) {
        float acc0 = 0.f, acc1 = 0.f, acc2 = 0.f;
        float a0 = y0, a1 = y1, a2 = y2;

#pragma unroll
        for (int st = 0; st < 4; ++st) {
            // ---- layer1 via fdot2 (bias folded into dot) ----
            half2_ a01 = __builtin_amdgcn_cvt_pkrtz(a0, a1);
            half2_ a2o = __builtin_amdgcn_cvt_pkrtz(a2, 1.0f);
            float hf[16];
#pragma unroll
            for (int jl = 0; jl < 16; ++jl) {
                hf[jl] = __builtin_amdgcn_fdot2(a01, w1p[jl],
                         __builtin_amdgcn_fdot2(a2o, w1q[jl], 0.f, false), false);
            }
            // B operands: B#1 <- hf[0..7] (k=half*8+j), B#2 <- hf[8..15]
            union { half2_ h2[4]; half8_ h8; } B1, B2;
#pragma unroll
            for (int pp = 0; pp < 4; ++pp) {
                B1.h2[pp] = relu_pk_f16(hf[2 * pp], hf[2 * pp + 1]);
                B2.h2[pp] = relu_pk_f16(hf[8 + 2 * pp], hf[8 + 2 * pp + 1]);
            }

            // ---- layer2: two chained 32x32x16 MFMAs (K=32) ----
            float16_ D = __builtin_amdgcn_mfma_f32_32x32x16_f16(W2T1.h8, B1.h8,
                         __builtin_amdgcn_mfma_f32_32x32x16_f16(W2T2.h8, B2.h8, Cb, 0, 0, 0), 0, 0, 0);

            // ---- relu -> packed f16 pairs (reg pair p matches w3h pairing) ----
            half2_ h[8];
#pragma unroll
            for (int p = 0; p < 8; ++p)
                h[p] = relu_pk_f16(D[2 * p], D[2 * p + 1]);

            // ---- layer3 via fdot2 (24) ----
            float p0 = 0.f, p1 = 0.f, p2 = 0.f;
#pragma unroll
            for (int p = 0; p < 8; ++p) {
                p0 = __builtin_amdgcn_fdot2(h[p], w3h[0][p], p0, false);
                p1 = __builtin_amdgcn_fdot2(h[p], w3h[1][p], p1, false);
                p2 = __builtin_amdgcn_fdot2(h[p], w3h[2][p], p2, false);
            }

            // ---- ONE reduction round: lane^32 holds the row's other 16 j2 ----
            p0 += __shfl_xor(p0, 32);
            p1 += __shfl_xor(p1, 32);
            p2 += __shfl_xor(p2, 32);
            float k0 = p0 + b30, k1 = p1 + b31, k2 = p2 + b32;

            const float ca = (st == 1 || st == 2) ? 2.0f : 1.0f;
            acc0 = fmaf(ca, k0, acc0); acc1 = fmaf(ca, k1, acc1); acc2 = fmaf(ca, k2, acc2);
            const float ci = (st == 2) ? dt : dt2;
            a0 = fmaf(ci, k0, y0); a1 = fmaf(ci, k1, y1); a2 = fmaf(ci, k2, y2);
        }
        y0 = fmaf(dt6, acc0, y0); y1 = fmaf(dt6, acc1, y1); y2 = fmaf(dt6, acc2, y2);

        // wave-uniform SALU fast path: most steps store nothing
        if ((smask >> s) & 1ull) {
            if (half == 0) {
#pragma unroll
                for (int j = 0; j < 8; ++j) {
                    if (sidx[j] == s) {
                        out[(size_t)j * B + row] = fmaf(y2, wo2, fmaf(y1, wo1, fmaf(y0, wo0, bo)));
                    }
                }
            }
        }
    }
}

extern "C" void kernel_launch(void* const* d_in, const int* in_sizes, int n_in,
                              void* d_out, int out_size, void* d_ws, size_t ws_size,
                              hipStream_t stream) {
    const float* x       = (const float*)d_in[0];
    const float* samples = (const float*)d_in[1];
    const float* w1      = (const float*)d_in[2];
    const float* b1      = (const float*)d_in[3];
    const float* w2      = (const float*)d_in[4];
    const float* b2      = (const float*)d_in[5];
    const float* w3      = (const float*)d_in[6];
    const float* b3      = (const float*)d_in[7];
    const float* w_out   = (const float*)d_in[8];
    const float* b_out   = (const float*)d_in[9];
    float* out = (float*)d_out;

    const int B = in_sizes[0] / 3;           // 131072
    const int rowsPerBlock = 128;            // 4 waves x 32 rows (1 group each)
    const int grid = (B + rowsPerBlock - 1) / rowsPerBlock;
    ode_rk4_mfma<<<grid, 256, 0, stream>>>(
        x, samples, w1, b1, w2, b2, w3, b3, w_out, b_out, out, B);
}